// Round 11
// baseline (79.644 us; speedup 1.0000x reference)
//
#include <hip/hip_runtime.h>

#define NTAGS 64
#define START_TAG 1
#define END_TAG 63
#define LN2F 0.69314718055994530942f
#define NSEG 8

typedef float v4f __attribute__((ext_vector_type(4)));

static __device__ __forceinline__ v4f fma4(float s, v4f b, v4f c) {
    return __builtin_elementwise_fma((v4f){s, s, s, s}, b, c);
}

// value from lane l^8 (row_ror:8 within each 16-lane row == xor8)
static __device__ __forceinline__ float xor8_get(float x) {
    return __int_as_float(__builtin_amdgcn_mov_dpp(__float_as_int(x), 0x128, 0xF, 0xF, true));
}
// convention-proof swap tricks: {r0,r1} = {send[l], send[l^K]} as a multiset
// under either output ordering, so r0+r1-send == send[l^K].
static __device__ __forceinline__ float xor16_get(float send) {
#if __has_builtin(__builtin_amdgcn_permlane16_swap)
    auto rr = __builtin_amdgcn_permlane16_swap(__float_as_uint(send), __float_as_uint(send),
                                               false, false);
    return (__uint_as_float((unsigned)rr[0]) + __uint_as_float((unsigned)rr[1])) - send;
#else
    return __shfl_xor(send, 16);
#endif
}
static __device__ __forceinline__ float xor32_get(float send) {
#if __has_builtin(__builtin_amdgcn_permlane32_swap)
    auto rr = __builtin_amdgcn_permlane32_swap(__float_as_uint(send), __float_as_uint(send),
                                               false, false);
    return (__uint_as_float((unsigned)rr[0]) + __uint_as_float((unsigned)rr[1])) - send;
#else
    return __shfl_xor(send, 32);
#endif
}

// ---------------------------------------------------------------------------
// Rank-1 segment decomposition, NSEG=8 segments of L=64 steps.
//   step op M_t = mask_t ? diag(exp(emit_t)) A^T : I,  A = exp(trans).
//   Chains per batch (all length L):
//     fwd: r_0 = S_0 p0 (exact), r_g = S_g 1 (probes, g=1..6)    types 0..6
//     bwd: l_g = S_g^T 1 (probes, g=1..6), l_7 = S_7^T u (exact) types 7..13
//   logZ = ln2*(e_r0 + e_r1..6 + e_l7)
//        + sum_{g=1}^{7} ln(l_g . r_{g-1}) - sum_{g=1}^{6} ln(sum l_g)
//   (probe-l exponents cancel between the + and - terms; verified R9 n=4.)
//
// Step body: 8-way split dot, 3 DS ops/step.
//   lane = 8q+g (g = out-group bits 0..2, q = chunk bits 3..5); lane reads
//   its 8-float chunk p[8q..8q+8) (2 uniform ds_read_b128, broadcast within
//   each 8-lane group); 16 fma4 = 64 MACs; reduce-scatter over k-bits via
//   xor8 (DPP row_ror:8), xor16/xor32 (permlane swaps) — all VALU pipe.
//   Keep-rule k_bit==q_bit per stage => lane ends with output index == lane.
// Rescale: lane-0 proxy exponent every 4 steps (R7-validated).
// ---------------------------------------------------------------------------
template <bool FWD>
static __device__ __forceinline__ void run_seg(const float* __restrict__ feats,
                                               const float* __restrict__ mask,
                                               const float* __restrict__ trans,
                                               float* __restrict__ outv,
                                               int* __restrict__ oute,
                                               int S, int t_begin, int L,
                                               int b, int init_mode, float* pl) {
    const int lane = threadIdx.x;
    const int g = lane & 7;
    const int ibase = lane & 0x38;        // 8 * chunk
    const int cb0 = (lane >> 3) & 1;
    const int cb1 = (lane >> 4) & 1;
    const int cb2 = (lane >> 5) & 1;
    const int wend = t_begin + L;

    // cA[i] = outputs k=0..3, cB[i] = outputs k=4..7, input ibase+i
    v4f cA[8], cB[8];
#pragma unroll
    for (int i = 0; i < 8; ++i) {
        if (FWD) {
            const float* rp = trans + (ibase + i) * NTAGS + g;
            cA[i] = (v4f){__expf(rp[0]),  __expf(rp[8]),  __expf(rp[16]), __expf(rp[24])};
            cB[i] = (v4f){__expf(rp[32]), __expf(rp[40]), __expf(rp[48]), __expf(rp[56])};
        } else {
            const float* cp = trans + ibase + i;
            cA[i] = (v4f){__expf(cp[(g)      * NTAGS]), __expf(cp[(g + 8)  * NTAGS]),
                          __expf(cp[(g + 16) * NTAGS]), __expf(cp[(g + 24) * NTAGS])};
            cB[i] = (v4f){__expf(cp[(g + 32) * NTAGS]), __expf(cp[(g + 40) * NTAGS]),
                          __expf(cp[(g + 48) * NTAGS]), __expf(cp[(g + 56) * NTAGS])};
        }
    }

    const float* fb = feats + (size_t)b * S * NTAGS;
    const float* mb = mask + (size_t)b * S;

    float p;
    if (init_mode == 0)      p = (lane == START_TAG) ? 1.0f : 0.0f;
    else if (init_mode == 1) p = 1.0f;
    else                     p = __expf(trans[lane * NTAGS + END_TAG]);
    int esum = 0;

#define TIDX(s) (FWD ? (t_begin + (s)) : (wend - 1 - (s)))

    float E[4], M[4];
    {
#pragma unroll
        for (int u = 0; u < 4; ++u) E[u] = __expf(fb[(size_t)TIDX(u) * NTAGS + lane]);
        if (FWD) {
            v4f v = *(const v4f*)(mb + t_begin);
            M[0] = v.x; M[1] = v.y; M[2] = v.z; M[3] = v.w;
        } else {
            v4f v = *(const v4f*)(mb + wend - 4);
            M[0] = v.w; M[1] = v.z; M[2] = v.y; M[3] = v.x;
        }
    }

#define STEP(Eu, Mu)                                                        \
    do {                                                                    \
        pl[lane] = FWD ? p : p * Eu; /* publish (in-order DS, same wave) */ \
        v4f q0 = ((const v4f*)(pl + ibase))[0];                             \
        v4f q1 = ((const v4f*)(pl + ibase))[1];                             \
        v4f accA = (v4f){q0.x, q0.x, q0.x, q0.x} * cA[0];                   \
        v4f accB = (v4f){q0.x, q0.x, q0.x, q0.x} * cB[0];                   \
        accA = fma4(q0.y, cA[1], accA); accB = fma4(q0.y, cB[1], accB);     \
        accA = fma4(q0.z, cA[2], accA); accB = fma4(q0.z, cB[2], accB);     \
        accA = fma4(q0.w, cA[3], accA); accB = fma4(q0.w, cB[3], accB);     \
        accA = fma4(q1.x, cA[4], accA); accB = fma4(q1.x, cB[4], accB);     \
        accA = fma4(q1.y, cA[5], accA); accB = fma4(q1.y, cB[5], accB);     \
        accA = fma4(q1.z, cA[6], accA); accB = fma4(q1.z, cB[6], accB);     \
        accA = fma4(q1.w, cA[7], accA); accB = fma4(q1.w, cB[7], accB);     \
        /* stage 1: xor8 over k bit0 (keep k0 == cb0) */                    \
        float sA01 = cb0 ? accA.x : accA.y, kA01 = cb0 ? accA.y : accA.x;   \
        float sA23 = cb0 ? accA.z : accA.w, kA23 = cb0 ? accA.w : accA.z;   \
        float sB45 = cb0 ? accB.x : accB.y, kB45 = cb0 ? accB.y : accB.x;   \
        float sB67 = cb0 ? accB.z : accB.w, kB67 = cb0 ? accB.w : accB.z;   \
        float sa = kA01 + xor8_get(sA01);                                   \
        float sb = kA23 + xor8_get(sA23);                                   \
        float sc = kB45 + xor8_get(sB45);                                   \
        float sd = kB67 + xor8_get(sB67);                                   \
        /* stage 2: xor16 over k bit1 (keep k1 == cb1) */                   \
        float s2s0 = cb1 ? sa : sb, s2k0 = cb1 ? sb : sa;                   \
        float s2s1 = cb1 ? sc : sd, s2k1 = cb1 ? sd : sc;                   \
        float u0 = s2k0 + xor16_get(s2s0);                                  \
        float u1 = s2k1 + xor16_get(s2s1);                                  \
        /* stage 3: xor32 over k bit2 (keep k2 == cb2) */                   \
        float s3s = cb2 ? u0 : u1, s3k = cb2 ? u1 : u0;                     \
        float nv = s3k + xor32_get(s3s);                                    \
        float pn = FWD ? nv * Eu : nv;                                      \
        p = (Mu != 0.0f) ? pn : p;                                          \
    } while (0)

    for (int t0_ = 0; t0_ < L; t0_ += 4) {
        float En[4];
        v4f Mn;
        const bool more = (t0_ + 4) < L;
        if (more) {
#pragma unroll
            for (int u = 0; u < 4; ++u)
                En[u] = fb[(size_t)TIDX(t0_ + 4 + u) * NTAGS + lane];
            Mn = FWD ? *(const v4f*)(mb + t_begin + t0_ + 4)
                     : *(const v4f*)(mb + wend - 8 - t0_);
        }

        STEP(E[0], M[0]);
        STEP(E[1], M[1]);
        STEP(E[2], M[2]);
        STEP(E[3], M[3]);

        // exact power-of-2 rescale via lane-0 proxy exponent (uniform)
        {
            int si = __builtin_amdgcn_readfirstlane(__float_as_int(p));
            int ef = (si >> 23) & 0xFF;
            if (ef != 0) {  // skip while lane0 is zero (one-hot start, masked)
                int ex = ef - 127;
                p = ldexpf(p, -ex);
                esum += ex;
            }
        }

        if (more) {
#pragma unroll
            for (int u = 0; u < 4; ++u) E[u] = __expf(En[u]);
            if (FWD) { M[0] = Mn.x; M[1] = Mn.y; M[2] = Mn.z; M[3] = Mn.w; }
            else     { M[0] = Mn.w; M[1] = Mn.z; M[2] = Mn.y; M[3] = Mn.x; }
        }
    }
#undef STEP
#undef TIDX

    outv[lane] = p;
    if (lane == 0) oute[0] = esum;
}

// ---------------------------------------------------------------------------
// blocks [tB,(t+1)B) for t=0..13: chain types; [14B,15B): gold path score
//   t in [0,7):  fwd segment t   (init: t==0 ? one-hot start : ones)
//   t in [7,14): bwd segment t-6 (init: t==13 ? u : ones)
// ---------------------------------------------------------------------------
__global__ __launch_bounds__(64, 4) void crf_chains(const float* __restrict__ feats,
                                                    const float* __restrict__ mask,
                                                    const int* __restrict__ tags,
                                                    const float* __restrict__ trans,
                                                    float* __restrict__ seg,
                                                    int* __restrict__ es,
                                                    float* __restrict__ gs,
                                                    int S, int L, int B) {
    const int bid = (int)blockIdx.x;
    const int lane = threadIdx.x;
    const int type = bid / B;
    const int b = bid - type * B;

    if (type == 14) {
        // ---- gold path score: one wave per batch ----
        const float* fb = feats + (size_t)b * S * NTAGS;
        const float* mb = mask + (size_t)b * S;
        const int* tb = tags + (size_t)b * S;
        float acc = 0.f, msum = 0.f;
        for (int t = lane; t < S; t += 64) {
            int cur = tb[t];
            int prev = (t == 0) ? START_TAG : tb[t - 1];
            float m = mb[t];
            acc += (fb[t * NTAGS + cur] + trans[prev * NTAGS + cur]) * m;
            msum += m;
        }
#pragma unroll
        for (int sh = 32; sh >= 1; sh >>= 1) {
            acc += __shfl_xor(acc, sh);
            msum += __shfl_xor(msum, sh);
        }
        if (lane == 0) {
            int seq_end = (int)(msum + 0.5f) - 1;
            int last = (seq_end >= 0) ? tb[seq_end] : START_TAG;
            gs[b] = acc + trans[last * NTAGS + END_TAG];
        }
        return;
    }

    __shared__ __align__(16) float pl[NTAGS];
    float* outv = seg + ((size_t)type * B + b) * NTAGS;
    int* oute = es + type * B + b;

    if (type < 7) {
        const int sg = type;
        run_seg<true>(feats, mask, trans, outv, oute, S, sg * L, L, b,
                      (sg == 0) ? 0 : 1, pl);
    } else {
        const int sg = type - 6;  // 1..7
        run_seg<false>(feats, mask, trans, outv, oute, S, sg * L, L, b,
                       (sg == 7) ? 2 : 1, pl);
    }
}

// ---------------------------------------------------------------------------
// per-batch bridging, one wave per batch:
// score = ln2*(es[0]+..+es[6]+es[13]) + sum_{g=1}^{7} ln(l_g.r_{g-1})
//       - sum_{g=1}^{6} ln(sum l_g);  scores[b] = score - gs[b]
// layout: r_g = seg[g], l_g = seg[6+g]
// ---------------------------------------------------------------------------
__global__ __launch_bounds__(512) void crf_finish(const float* __restrict__ seg,
                                                  const int* __restrict__ es,
                                                  const float* __restrict__ gs,
                                                  float* __restrict__ scores, int B) {
    const int tid = threadIdx.x;
    const int wave = tid >> 6, lane = tid & 63;
    const int b = blockIdx.x * 8 + wave;
    if (b >= B) return;

    float r[7], l[7];
#pragma unroll
    for (int gi = 0; gi < 7; ++gi)
        r[gi] = seg[((size_t)gi * B + b) * NTAGS + lane];
#pragma unroll
    for (int gi = 0; gi < 7; ++gi)
        l[gi] = seg[((size_t)(7 + gi) * B + b) * NTAGS + lane];  // l_{gi+1}

    float d[7], s[6];
#pragma unroll
    for (int gi = 0; gi < 7; ++gi) d[gi] = l[gi] * r[gi];  // l_{g}.r_{g-1}
#pragma unroll
    for (int gi = 0; gi < 6; ++gi) s[gi] = l[gi];
#pragma unroll
    for (int sh = 32; sh >= 1; sh >>= 1) {
#pragma unroll
        for (int gi = 0; gi < 7; ++gi) d[gi] += __shfl_xor(d[gi], sh);
#pragma unroll
        for (int gi = 0; gi < 6; ++gi) s[gi] += __shfl_xor(s[gi], sh);
    }
    if (lane == 0) {
        float score = (float)(es[0 * B + b] + es[1 * B + b] + es[2 * B + b] +
                              es[3 * B + b] + es[4 * B + b] + es[5 * B + b] +
                              es[6 * B + b] + es[13 * B + b]) * LN2F;
#pragma unroll
        for (int gi = 0; gi < 7; ++gi) score += __logf(d[gi]);
#pragma unroll
        for (int gi = 0; gi < 6; ++gi) score -= __logf(s[gi]);
        scores[b] = score - gs[b];
    }
}

__global__ __launch_bounds__(1024) void crf_mean(const float* __restrict__ scores,
                                                 float* __restrict__ out, int B) {
    const int tid = threadIdx.x;
    float a = 0.f;
    for (int i = tid; i < B; i += 1024) a += scores[i];
#pragma unroll
    for (int sh = 32; sh >= 1; sh >>= 1) a += __shfl_xor(a, sh);
    __shared__ float buf[16];
    if ((tid & 63) == 0) buf[tid >> 6] = a;
    __syncthreads();
    if (tid == 0) {
        float s = 0.f;
#pragma unroll
        for (int i = 0; i < 16; ++i) s += buf[i];
        out[0] = s / (float)B;
    }
}

extern "C" void kernel_launch(void* const* d_in, const int* in_sizes, int n_in,
                              void* d_out, int out_size, void* d_ws, size_t ws_size,
                              hipStream_t stream) {
    const float* feats = (const float*)d_in[0];
    const float* mask  = (const float*)d_in[1];
    const int*   tags  = (const int*)d_in[2];
    const float* trans = (const float*)d_in[3];
    float* out = (float*)d_out;

    const int S = 512;              // reference shape
    const int B = in_sizes[1] / S;  // mask is (B,S)
    const int L = S / NSEG;         // 8 segments of 64 steps

    float* seg = (float*)d_ws;                       // [14][B][64]
    int* es = (int*)(seg + (size_t)14 * B * NTAGS);  // [14][B]
    float* gs = (float*)(es + 14 * B);               // [B]
    float* scores = gs + B;                          // [B]

    crf_chains<<<15 * B, 64, 0, stream>>>(feats, mask, tags, trans, seg, es, gs, S, L, B);
    crf_finish<<<(B + 7) / 8, 512, 0, stream>>>(seg, es, gs, scores, B);
    crf_mean<<<1, 1024, 0, stream>>>(scores, out, B);
}

// Round 12
// 67.085 us; speedup vs baseline: 1.1872x; 1.1872x over previous
//
#include <hip/hip_runtime.h>

#define NTAGS 64
#define START_TAG 1
#define END_TAG 63
#define LN2F 0.69314718055994530942f

typedef float v4f __attribute__((ext_vector_type(4)));

static __device__ __forceinline__ v4f fma4(float s, v4f b, v4f c) {
    return __builtin_elementwise_fma((v4f){s, s, s, s}, b, c);
}

// value from lane l^8 (row_ror:8 within each 16-lane row == xor8)
static __device__ __forceinline__ float xor8_get(float x) {
    return __int_as_float(__builtin_amdgcn_mov_dpp(__float_as_int(x), 0x128, 0xF, 0xF, true));
}
// convention-proof: {r0,r1} = {send[l], send[l^32]} as a multiset under either
// output ordering of permlane32_swap, so r0+r1-send == send[l^32].
static __device__ __forceinline__ float xor32_get(float send) {
#if __has_builtin(__builtin_amdgcn_permlane32_swap)
    auto rr = __builtin_amdgcn_permlane32_swap(__float_as_uint(send), __float_as_uint(send),
                                               false, false);
    return (__uint_as_float((unsigned)rr[0]) + __uint_as_float((unsigned)rr[1])) - send;
#else
    return __shfl_xor(send, 32);
#endif
}

// ---------------------------------------------------------------------------
// Rank-1 segment decomposition, 4 segments of L=S/4 (R9/R10-proven, absmax 0):
//   r0=S0 p0, r1=S1 1, r2=S2 1 (fwd); l1=S1^T 1, l2=S2^T 1, l3=S3^T u (bwd)
//   logZ = (e0+er1+er2+el3) ln2 + ln(l1.r0) - ln(sum l1)
//        + ln(l2.r1) - ln(sum l2) + ln(l3.r2)
//
// Step body (R10-proven, o=4 balance point): 4-way split dot, 5 DS ops/step.
//   lane chunk = bit3 + 2*bit5; 4 uniform ds_read_b128; 16 fma4 (64 MACs);
//   reduce-scatter: xor8 via DPP row_ror:8, xor32 via permlane32_swap.
// NEW vs R10: 4 waves per 256-thread block (private LDS slices, no barriers)
// for ~2x resident waves/CU, and 8-step-deep E/M double-buffered prefetch so
// the ~900cy global-load latency hides under ~1600cy of compute.
// Rescale: lane-0 proxy exponent every 4 steps (R7-validated).
// ---------------------------------------------------------------------------
template <bool FWD>
static __device__ __forceinline__ void run_seg(const float* __restrict__ feats,
                                               const float* __restrict__ mask,
                                               const float* __restrict__ trans,
                                               float* __restrict__ outv,
                                               int* __restrict__ oute,
                                               int S, int t_begin, int L,
                                               int b, int init_mode, float* pl) {
    const int lane = threadIdx.x & 63;
    const int g0 = lane & 0x17;          // output-group bits 0,1,2,4
    const int cb0 = (lane >> 3) & 1;     // chunk bit 0
    const int cb1 = (lane >> 5) & 1;     // chunk bit 1
    const int ibase = (cb0 + 2 * cb1) * 16;
    const int wend = t_begin + L;

    // c4[i][k] = A[input ibase+i][output o(k)] (fwd) / A[o(k)][ibase+i] (bwd)
    v4f c4[16];
#pragma unroll
    for (int i = 0; i < 16; ++i) {
        if (FWD) {
            const float* rp = trans + (ibase + i) * NTAGS;
            c4[i] = (v4f){__expf(rp[g0]), __expf(rp[g0 + 8]),
                          __expf(rp[g0 + 32]), __expf(rp[g0 + 40])};
        } else {
            c4[i] = (v4f){__expf(trans[(g0)      * NTAGS + ibase + i]),
                          __expf(trans[(g0 + 8)  * NTAGS + ibase + i]),
                          __expf(trans[(g0 + 32) * NTAGS + ibase + i]),
                          __expf(trans[(g0 + 40) * NTAGS + ibase + i])};
        }
    }

    const float* fb = feats + (size_t)b * S * NTAGS;
    const float* mb = mask + (size_t)b * S;

    float p;
    if (init_mode == 0)      p = (lane == START_TAG) ? 1.0f : 0.0f;
    else if (init_mode == 1) p = 1.0f;
    else                     p = __expf(trans[lane * NTAGS + END_TAG]);
    int esum = 0;

#define TIDX(s) (FWD ? (t_begin + (s)) : (wend - 1 - (s)))
    // v4f of mask covering steps s..s+3 (component order raw; reversed for bwd)
#define MLOAD(s) (FWD ? *(const v4f*)(mb + t_begin + (s)) \
                      : *(const v4f*)(mb + wend - 4 - (s)))

    // ---- deep prefetch: Ecur (exp'd, steps t0..t0+3), Eraw (t0+4..t0+7) ----
    float Ecur[4], Eraw[4];
    v4f Mcur, Mnext;
    {
#pragma unroll
        for (int u = 0; u < 4; ++u) Ecur[u] = fb[(size_t)TIDX(u) * NTAGS + lane];
        Mcur = MLOAD(0);
#pragma unroll
        for (int u = 0; u < 4; ++u) Eraw[u] = fb[(size_t)TIDX(4 + u) * NTAGS + lane];
        Mnext = MLOAD(4);
#pragma unroll
        for (int u = 0; u < 4; ++u) Ecur[u] = __expf(Ecur[u]);
    }

#define STEP(Eu, Mu)                                                        \
    do {                                                                    \
        pl[lane] = FWD ? p : p * Eu; /* publish (in-order DS, same wave) */ \
        v4f q0 = ((const v4f*)(pl + ibase))[0];                             \
        v4f q1 = ((const v4f*)(pl + ibase))[1];                             \
        v4f q2 = ((const v4f*)(pl + ibase))[2];                             \
        v4f q3 = ((const v4f*)(pl + ibase))[3];                             \
        v4f acc = (v4f){q0.x, q0.x, q0.x, q0.x} * c4[0];                    \
        acc = fma4(q0.y, c4[1], acc);                                       \
        acc = fma4(q0.z, c4[2], acc);                                       \
        acc = fma4(q0.w, c4[3], acc);                                       \
        acc = fma4(q1.x, c4[4], acc);                                       \
        acc = fma4(q1.y, c4[5], acc);                                       \
        acc = fma4(q1.z, c4[6], acc);                                       \
        acc = fma4(q1.w, c4[7], acc);                                       \
        acc = fma4(q2.x, c4[8], acc);                                       \
        acc = fma4(q2.y, c4[9], acc);                                       \
        acc = fma4(q2.z, c4[10], acc);                                      \
        acc = fma4(q2.w, c4[11], acc);                                      \
        acc = fma4(q3.x, c4[12], acc);                                      \
        acc = fma4(q3.y, c4[13], acc);                                      \
        acc = fma4(q3.z, c4[14], acc);                                      \
        acc = fma4(q3.w, c4[15], acc);                                      \
        /* stage 1: xor8 over k bit0 (keep k0 == cb0) */                    \
        float send0 = cb0 ? acc.x : acc.y;                                  \
        float send1 = cb0 ? acc.z : acc.w;                                  \
        float keep0 = cb0 ? acc.y : acc.x;                                  \
        float keep1 = cb0 ? acc.w : acc.z;                                  \
        float t0v = keep0 + xor8_get(send0);                                \
        float t1v = keep1 + xor8_get(send1);                                \
        /* stage 2: xor32 over k bit1 (keep k1 == cb1) */                   \
        float sendU = cb1 ? t0v : t1v;                                      \
        float keepU = cb1 ? t1v : t0v;                                      \
        float nv = keepU + xor32_get(sendU);                                \
        float pn = FWD ? nv * Eu : nv;                                      \
        p = (Mu != 0.0f) ? pn : p;                                          \
    } while (0)

    for (int t0_ = 0; t0_ < L; t0_ += 4) {
        const bool have2 = (t0_ + 8) < L;
        float E2[4];
        v4f M2;
        if (have2) {
#pragma unroll
            for (int u = 0; u < 4; ++u)
                E2[u] = fb[(size_t)TIDX(t0_ + 8 + u) * NTAGS + lane];
            M2 = MLOAD(t0_ + 8);
        }

        float M0, M1v, M2v, M3;
        if (FWD) { M0 = Mcur.x; M1v = Mcur.y; M2v = Mcur.z; M3 = Mcur.w; }
        else     { M0 = Mcur.w; M1v = Mcur.z; M2v = Mcur.y; M3 = Mcur.x; }

        STEP(Ecur[0], M0);
        STEP(Ecur[1], M1v);
        STEP(Ecur[2], M2v);
        STEP(Ecur[3], M3);

        // exact power-of-2 rescale via lane-0 proxy exponent (uniform)
        {
            int si = __builtin_amdgcn_readfirstlane(__float_as_int(p));
            int ef = (si >> 23) & 0xFF;
            if (ef != 0) {  // skip while lane0 is zero (one-hot start, masked)
                int ex = ef - 127;
                p = ldexpf(p, -ex);
                esum += ex;
            }
        }

        if (t0_ + 4 < L) {
#pragma unroll
            for (int u = 0; u < 4; ++u) Ecur[u] = __expf(Eraw[u]);
            Mcur = Mnext;
            if (have2) {
#pragma unroll
                for (int u = 0; u < 4; ++u) Eraw[u] = E2[u];
                Mnext = M2;
            }
        }
    }
#undef STEP
#undef TIDX
#undef MLOAD

    outv[lane] = p;
    if (lane == 0) oute[0] = esum;
}

// ---------------------------------------------------------------------------
// 256-thread blocks, 4 independent chain waves each (private LDS slices).
// wave id w = blockIdx.x*4 + (tid>>6); type = w/B in 0..5 chains, 6 = gold.
// ---------------------------------------------------------------------------
__global__ __launch_bounds__(256) void crf_chains(const float* __restrict__ feats,
                                                  const float* __restrict__ mask,
                                                  const int* __restrict__ tags,
                                                  const float* __restrict__ trans,
                                                  float* __restrict__ seg,
                                                  int* __restrict__ es,
                                                  float* __restrict__ gs,
                                                  int S, int L, int B) {
    const int widx = threadIdx.x >> 6;
    const int lane = threadIdx.x & 63;
    const int w = (int)blockIdx.x * 4 + widx;
    if (w >= 7 * B) return;
    const int type = w / B;
    const int b = w - type * B;

    if (type == 6) {
        // ---- gold path score: one wave per batch ----
        const float* fb = feats + (size_t)b * S * NTAGS;
        const float* mb = mask + (size_t)b * S;
        const int* tb = tags + (size_t)b * S;
        float acc = 0.f, msum = 0.f;
        for (int t = lane; t < S; t += 64) {
            int cur = tb[t];
            int prev = (t == 0) ? START_TAG : tb[t - 1];
            float m = mb[t];
            acc += (fb[t * NTAGS + cur] + trans[prev * NTAGS + cur]) * m;
            msum += m;
        }
#pragma unroll
        for (int sh = 32; sh >= 1; sh >>= 1) {
            acc += __shfl_xor(acc, sh);
            msum += __shfl_xor(msum, sh);
        }
        if (lane == 0) {
            int seq_end = (int)(msum + 0.5f) - 1;
            int last = (seq_end >= 0) ? tb[seq_end] : START_TAG;
            gs[b] = acc + trans[last * NTAGS + END_TAG];
        }
        return;
    }

    __shared__ __align__(16) float pl4[4][NTAGS];
    float* pl = pl4[widx];
    float* outv = seg + ((size_t)type * B + b) * NTAGS;
    int* oute = es + type * B + b;

    switch (type) {
        case 0: run_seg<true >(feats, mask, trans, outv, oute, S, 0 * L, L, b, 0, pl); break;
        case 1: run_seg<true >(feats, mask, trans, outv, oute, S, 1 * L, L, b, 1, pl); break;
        case 2: run_seg<true >(feats, mask, trans, outv, oute, S, 2 * L, L, b, 1, pl); break;
        case 3: run_seg<false>(feats, mask, trans, outv, oute, S, 1 * L, L, b, 1, pl); break;
        case 4: run_seg<false>(feats, mask, trans, outv, oute, S, 2 * L, L, b, 1, pl); break;
        case 5: run_seg<false>(feats, mask, trans, outv, oute, S, 3 * L, L, b, 2, pl); break;
    }
}

// ---------------------------------------------------------------------------
// per-batch bridging, one wave per batch (R10-proven):
// score = (e0+er1+er2+el3) ln2 + ln(l1.r0) - ln(sum l1)
//       + ln(l2.r1) - ln(sum l2) + ln(l3.r2);  scores[b] = score - gs[b]
// ---------------------------------------------------------------------------
__global__ __launch_bounds__(512) void crf_finish(const float* __restrict__ seg,
                                                  const int* __restrict__ es,
                                                  const float* __restrict__ gs,
                                                  float* __restrict__ scores, int B) {
    const int tid = threadIdx.x;
    const int wave = tid >> 6, lane = tid & 63;
    const int b = blockIdx.x * 8 + wave;
    if (b >= B) return;

    float r0 = seg[((size_t)0 * B + b) * NTAGS + lane];
    float r1 = seg[((size_t)1 * B + b) * NTAGS + lane];
    float r2 = seg[((size_t)2 * B + b) * NTAGS + lane];
    float l1 = seg[((size_t)3 * B + b) * NTAGS + lane];
    float l2 = seg[((size_t)4 * B + b) * NTAGS + lane];
    float l3 = seg[((size_t)5 * B + b) * NTAGS + lane];
    float d1 = l1 * r0, d2 = l2 * r1, d3 = l3 * r2;
    float s1 = l1, s2 = l2;
#pragma unroll
    for (int sh = 32; sh >= 1; sh >>= 1) {
        d1 += __shfl_xor(d1, sh);
        d2 += __shfl_xor(d2, sh);
        d3 += __shfl_xor(d3, sh);
        s1 += __shfl_xor(s1, sh);
        s2 += __shfl_xor(s2, sh);
    }
    if (lane == 0) {
        float score = (float)(es[0 * B + b] + es[1 * B + b] + es[2 * B + b] +
                              es[5 * B + b]) * LN2F
                    + __logf(d1) - __logf(s1)
                    + __logf(d2) - __logf(s2)
                    + __logf(d3);
        scores[b] = score - gs[b];
    }
}

__global__ __launch_bounds__(1024) void crf_mean(const float* __restrict__ scores,
                                                 float* __restrict__ out, int B) {
    const int tid = threadIdx.x;
    float a = 0.f;
    for (int i = tid; i < B; i += 1024) a += scores[i];
#pragma unroll
    for (int sh = 32; sh >= 1; sh >>= 1) a += __shfl_xor(a, sh);
    __shared__ float buf[16];
    if ((tid & 63) == 0) buf[tid >> 6] = a;
    __syncthreads();
    if (tid == 0) {
        float s = 0.f;
#pragma unroll
        for (int i = 0; i < 16; ++i) s += buf[i];
        out[0] = s / (float)B;
    }
}

extern "C" void kernel_launch(void* const* d_in, const int* in_sizes, int n_in,
                              void* d_out, int out_size, void* d_ws, size_t ws_size,
                              hipStream_t stream) {
    const float* feats = (const float*)d_in[0];
    const float* mask  = (const float*)d_in[1];
    const int*   tags  = (const int*)d_in[2];
    const float* trans = (const float*)d_in[3];
    float* out = (float*)d_out;

    const int S = 512;              // reference shape
    const int B = in_sizes[1] / S;  // mask is (B,S)
    const int L = S / 4;            // 4 segments of 128 steps

    float* seg = (float*)d_ws;                      // [6][B][64]
    int* es = (int*)(seg + (size_t)6 * B * NTAGS);  // [6][B]
    float* gs = (float*)(es + 6 * B);               // [B]
    float* scores = gs + B;                         // [B]

    const int nwaves = 7 * B;
    crf_chains<<<(nwaves + 3) / 4, 256, 0, stream>>>(feats, mask, tags, trans,
                                                     seg, es, gs, S, L, B);
    crf_finish<<<(B + 7) / 8, 512, 0, stream>>>(seg, es, gs, scores, B);
    crf_mean<<<1, 1024, 0, stream>>>(scores, out, B);
}

// Round 13
// 40.527 us; speedup vs baseline: 1.9652x; 1.6553x over previous
//
#include <hip/hip_runtime.h>
#include <hip/hip_bf16.h>

#define NTAGS 64
#define START_TAG 1
#define END_TAG 63
#define LN2F 0.69314718055994530942f
#define NSEG 16

typedef float v4f __attribute__((ext_vector_type(4)));
typedef short s16x8 __attribute__((ext_vector_type(8)));

static __device__ __forceinline__ unsigned short f2bfu(float x) {
    union { __hip_bfloat16 h; unsigned short s; } u;
    u.h = __float2bfloat16(x);
    return u.s;
}
static __device__ __forceinline__ unsigned int packbf(float lo, float hi) {
    return (unsigned int)f2bfu(lo) | ((unsigned int)f2bfu(hi) << 16);
}
// convention-proof partner fetch (R10/R11-proven): {r0,r1} = {v_l, v_l^K} as a
// multiset under either output ordering, so r0+r1-v == v_l^K.
static __device__ __forceinline__ float xor16_get(float send) {
#if __has_builtin(__builtin_amdgcn_permlane16_swap)
    auto rr = __builtin_amdgcn_permlane16_swap(__float_as_uint(send), __float_as_uint(send),
                                               false, false);
    return (__uint_as_float((unsigned)rr[0]) + __uint_as_float((unsigned)rr[1])) - send;
#else
    return __shfl_xor(send, 16);
#endif
}
static __device__ __forceinline__ float xor32_get(float send) {
#if __has_builtin(__builtin_amdgcn_permlane32_swap)
    auto rr = __builtin_amdgcn_permlane32_swap(__float_as_uint(send), __float_as_uint(send),
                                               false, false);
    return (__uint_as_float((unsigned)rr[0]) + __uint_as_float((unsigned)rr[1])) - send;
#else
    return __shfl_xor(send, 32);
#endif
}
static __device__ __forceinline__ v4f max4(v4f a, v4f b) {
    return __builtin_elementwise_max(a, b);
}

// ---------------------------------------------------------------------------
// MFMA chain: one wave advances 16 batches of ONE rank-1 segment chain.
//   fwd: P' = (A^T P) ∘ E_t ; bwd: W' = A (E_t ∘ W) ;  A = exp(trans)
// State: f32 in MFMA D layout (col=lane&15=batch c, row=4*(lane>>4)+r=tag
// within tile m; tag = 16m+4g+r). Per step:
//   pack state→bf16 dwords (tag pairs), write to LDS in B-layout groups
//   (XOR-swizzled, 4x ds_write_b64), read 2x ds_read_b128 → B frags
//   (col=c=batch, k=8g+e), 8 MFMA vs resident A frags (row=c=tag-in-tile,
//   k=8g+e), E-multiply in f32, per-batch mask select.
// Rescale: every 8 steps, per-batch max via permlane16/32 + frexp (exact).
// ---------------------------------------------------------------------------
template <bool FWD>
static __device__ __forceinline__ void run_seg_mfma(
    const float* __restrict__ feats, const float* __restrict__ mask,
    const float* __restrict__ trans, float* __restrict__ outv,
    int* __restrict__ oute, int S, int t_begin, int L, int b0, int init_mode,
    unsigned int* __restrict__ lds) {
    const int lane = threadIdx.x & 63;
    const int c = lane & 15, g = lane >> 4;
    const int swz = c & 7;

    // A fragments (resident): Af[m][kk] elem e = M[16m + c][k = 32kk + 8g + e]
    // fwd M = A^T -> trans[k][16m+c]; bwd M = A -> trans[16m+c][k]
    s16x8 Af[4][2];
#pragma unroll
    for (int m = 0; m < 4; ++m)
#pragma unroll
        for (int kk = 0; kk < 2; ++kk)
#pragma unroll
            for (int e = 0; e < 8; ++e) {
                float tv = FWD ? trans[(32 * kk + 8 * g + e) * NTAGS + 16 * m + c]
                               : trans[(16 * m + c) * NTAGS + 32 * kk + 8 * g + e];
                Af[m][kk][e] = (short)f2bfu(__expf(tv));
            }

    // state D[m], component r = state[batch c][tag 16m+4g+r]
    v4f D[4];
    if (init_mode == 0) {
#pragma unroll
        for (int m = 0; m < 4; ++m) D[m] = (v4f){0.f, 0.f, 0.f, 0.f};
        if (g == 0) D[0].y = 1.0f;  // tag 1 == 16*0+4*0+1
    } else if (init_mode == 1) {
#pragma unroll
        for (int m = 0; m < 4; ++m) D[m] = (v4f){1.f, 1.f, 1.f, 1.f};
    } else {
#pragma unroll
        for (int m = 0; m < 4; ++m) {
            D[m].x = __expf(trans[(16 * m + 4 * g + 0) * NTAGS + END_TAG]);
            D[m].y = __expf(trans[(16 * m + 4 * g + 1) * NTAGS + END_TAG]);
            D[m].z = __expf(trans[(16 * m + 4 * g + 2) * NTAGS + END_TAG]);
            D[m].w = __expf(trans[(16 * m + 4 * g + 3) * NTAGS + END_TAG]);
        }
    }

    const float* fb = feats + (size_t)(b0 + c) * S * NTAGS;
    const float* mb = mask + (size_t)(b0 + c) * S;
    int esum = 0;

#define TT(sv) (FWD ? (t_begin + (sv)) : (t_begin + L - 1 - (sv)))
#define ELOAD(Ereg, Mreg, sv)                                                     \
    do {                                                                          \
        _Pragma("unroll") for (int n = 0; n < 4; ++n)                             \
            Ereg[n] = *(const v4f*)(fb + (size_t)TT(sv) * NTAGS + 16 * n + 4 * g);\
        Mreg = mb[TT(sv)];                                                        \
    } while (0)

#define STEPX(Ereg, Mv)                                                           \
    do {                                                                          \
        v4f Ex[4];                                                                \
        _Pragma("unroll") for (int n = 0; n < 4; ++n) {                           \
            Ex[n].x = __expf(Ereg[n].x); Ex[n].y = __expf(Ereg[n].y);             \
            Ex[n].z = __expf(Ereg[n].z); Ex[n].w = __expf(Ereg[n].w);             \
        }                                                                         \
        _Pragma("unroll") for (int n = 0; n < 4; ++n) {                           \
            v4f sv = FWD ? D[n] : D[n] * Ex[n];                                   \
            unsigned int u0 = packbf(sv.x, sv.y);                                 \
            unsigned int u1 = packbf(sv.z, sv.w);                                 \
            int G = 2 * n + (g >> 1);                                             \
            int di = c * 36 + ((G ^ swz) << 2) + 2 * (g & 1);                     \
            *reinterpret_cast<uint2*>(lds + di) = make_uint2(u0, u1);             \
        }                                                                         \
        s16x8 Bf0, Bf1;                                                           \
        { int di = c * 36 + ((g ^ swz) << 2);       Bf0 = *(const s16x8*)(lds + di); } \
        { int di = c * 36 + (((4 + g) ^ swz) << 2); Bf1 = *(const s16x8*)(lds + di); } \
        v4f Dm[4];                                                                \
        _Pragma("unroll") for (int m = 0; m < 4; ++m) {                           \
            v4f z = (v4f){0.f, 0.f, 0.f, 0.f};                                    \
            Dm[m] = __builtin_amdgcn_mfma_f32_16x16x32_bf16(Af[m][0], Bf0, z, 0, 0, 0); \
            Dm[m] = __builtin_amdgcn_mfma_f32_16x16x32_bf16(Af[m][1], Bf1, Dm[m], 0, 0, 0); \
        }                                                                         \
        if (FWD) {                                                                \
            _Pragma("unroll") for (int m = 0; m < 4; ++m) Dm[m] = Dm[m] * Ex[m];  \
        }                                                                         \
        bool act = (Mv != 0.0f);                                                  \
        _Pragma("unroll") for (int m = 0; m < 4; ++m) D[m] = act ? Dm[m] : D[m];  \
    } while (0)

    // 4-set E/M prefetch rotation, distance 2 steps (static indexing)
    v4f EA[4], EB[4], EC[4], ED[4];
    float MA, MB, MC, MD;
    ELOAD(EA, MA, 0);
    ELOAD(EB, MB, 1);

    for (int s = 0; s < L; s += 4) {
        ELOAD(EC, MC, s + 2);
        ELOAD(ED, MD, s + 3);
        STEPX(EA, MA);
        STEPX(EB, MB);
        if (s + 4 < L) {
            ELOAD(EA, MA, s + 4);
            ELOAD(EB, MB, s + 5);
        }
        STEPX(EC, MC);
        STEPX(ED, MD);
        if (((s + 4) & 7) == 0) {  // after steps 8,16,24,...
            v4f mm = max4(max4(D[0], D[1]), max4(D[2], D[3]));
            float mx = fmaxf(fmaxf(mm.x, mm.y), fmaxf(mm.z, mm.w));
            mx = fmaxf(mx, xor16_get(mx));
            mx = fmaxf(mx, xor32_get(mx));
            int ex;
            (void)frexpf(mx, &ex);
#pragma unroll
            for (int m = 0; m < 4; ++m) {
                D[m].x = ldexpf(D[m].x, -ex);
                D[m].y = ldexpf(D[m].y, -ex);
                D[m].z = ldexpf(D[m].z, -ex);
                D[m].w = ldexpf(D[m].w, -ex);
            }
            esum += ex;
        }
    }
#undef STEPX
#undef ELOAD
#undef TT

    float* oc = outv + (size_t)(b0 + c) * NTAGS;
#pragma unroll
    for (int m = 0; m < 4; ++m) *(v4f*)(oc + 16 * m + 4 * g) = D[m];
    if (g == 0) oute[b0 + c] = esum;
}

// ---------------------------------------------------------------------------
// blocks [0, 30*B/16): chain waves (type = bid>>5 with B=512 -> 32 groups);
// blocks [30*B/16, +B): gold path score.
// types 0..14: fwd segs 0..14 (init: seg0 one-hot, else ones)
// types 15..29: bwd segs 1..15 (init: seg15 u, else ones)
// ---------------------------------------------------------------------------
__global__ __launch_bounds__(64) void crf_chains(const float* __restrict__ feats,
                                                 const float* __restrict__ mask,
                                                 const int* __restrict__ tags,
                                                 const float* __restrict__ trans,
                                                 float* __restrict__ seg,
                                                 int* __restrict__ es,
                                                 float* __restrict__ gs,
                                                 int S, int L, int B, int nchain) {
    const int bid = (int)blockIdx.x;
    const int lane = threadIdx.x;

    if (bid >= nchain) {
        // ---- gold path score: one wave per batch ----
        const int b = bid - nchain;
        const float* fb = feats + (size_t)b * S * NTAGS;
        const float* mb = mask + (size_t)b * S;
        const int* tb = tags + (size_t)b * S;
        float acc = 0.f, msum = 0.f;
        for (int t = lane; t < S; t += 64) {
            int cur = tb[t];
            int prev = (t == 0) ? START_TAG : tb[t - 1];
            float m = mb[t];
            acc += (fb[t * NTAGS + cur] + trans[prev * NTAGS + cur]) * m;
            msum += m;
        }
#pragma unroll
        for (int sh = 32; sh >= 1; sh >>= 1) {
            acc += __shfl_xor(acc, sh);
            msum += __shfl_xor(msum, sh);
        }
        if (lane == 0) {
            int seq_end = (int)(msum + 0.5f) - 1;
            int last = (seq_end >= 0) ? tb[seq_end] : START_TAG;
            gs[b] = acc + trans[last * NTAGS + END_TAG];
        }
        return;
    }

    __shared__ unsigned int lds[16 * 36];  // 2304 B, one wave per block
    const int ngrp = B / 16;
    const int type = bid / ngrp;
    const int grp = bid - type * ngrp;
    const int b0 = grp * 16;

    float* outv = seg + (size_t)type * B * NTAGS;
    int* oute = es + type * B;

    if (type < 15) {
        run_seg_mfma<true>(feats, mask, trans, outv, oute, S, type * L, L, b0,
                           (type == 0) ? 0 : 1, lds);
    } else {
        const int sg = type - 14;  // 1..15
        run_seg_mfma<false>(feats, mask, trans, outv, oute, S, sg * L, L, b0,
                            (sg == 15) ? 2 : 1, lds);
    }
}

// ---------------------------------------------------------------------------
// per-batch bridging, one wave per batch:
// score = ln2*(sum_{g=0}^{14} es_r[g] + es_l[15])
//       + sum_{g=1}^{15} ln(l_g . r_{g-1}) - sum_{g=1}^{14} ln(sum l_g)
// r_g = seg[g], l_g = seg[14+g].  scores[b] = score - gs[b]
// ---------------------------------------------------------------------------
__global__ __launch_bounds__(512) void crf_finish(const float* __restrict__ seg,
                                                  const int* __restrict__ es,
                                                  const float* __restrict__ gs,
                                                  float* __restrict__ scores, int B) {
    const int tid = threadIdx.x;
    const int wave = tid >> 6, lane = tid & 63;
    const int b = blockIdx.x * 8 + wave;
    if (b >= B) return;

    float rv[15], lv[15];
#pragma unroll
    for (int gi = 0; gi < 15; ++gi)
        rv[gi] = seg[((size_t)gi * B + b) * NTAGS + lane];
#pragma unroll
    for (int gi = 0; gi < 15; ++gi)
        lv[gi] = seg[((size_t)(15 + gi) * B + b) * NTAGS + lane];  // l_{gi+1}

    float d[15], sl[14];
#pragma unroll
    for (int gi = 0; gi < 15; ++gi) d[gi] = lv[gi] * rv[gi];  // l_{g} . r_{g-1}
#pragma unroll
    for (int gi = 0; gi < 14; ++gi) sl[gi] = lv[gi];
#pragma unroll
    for (int sh = 32; sh >= 1; sh >>= 1) {
#pragma unroll
        for (int gi = 0; gi < 15; ++gi) d[gi] += __shfl_xor(d[gi], sh);
#pragma unroll
        for (int gi = 0; gi < 14; ++gi) sl[gi] += __shfl_xor(sl[gi], sh);
    }
    if (lane == 0) {
        int esum = es[29 * B + b];
#pragma unroll
        for (int gi = 0; gi < 15; ++gi) esum += es[gi * B + b];
        float score = (float)esum * LN2F;
#pragma unroll
        for (int gi = 0; gi < 15; ++gi) score += __logf(d[gi]);
#pragma unroll
        for (int gi = 0; gi < 14; ++gi) score -= __logf(sl[gi]);
        scores[b] = score - gs[b];
    }
}

__global__ __launch_bounds__(1024) void crf_mean(const float* __restrict__ scores,
                                                 float* __restrict__ out, int B) {
    const int tid = threadIdx.x;
    float a = 0.f;
    for (int i = tid; i < B; i += 1024) a += scores[i];
#pragma unroll
    for (int sh = 32; sh >= 1; sh >>= 1) a += __shfl_xor(a, sh);
    __shared__ float buf[16];
    if ((tid & 63) == 0) buf[tid >> 6] = a;
    __syncthreads();
    if (tid == 0) {
        float s = 0.f;
#pragma unroll
        for (int i = 0; i < 16; ++i) s += buf[i];
        out[0] = s / (float)B;
    }
}

extern "C" void kernel_launch(void* const* d_in, const int* in_sizes, int n_in,
                              void* d_out, int out_size, void* d_ws, size_t ws_size,
                              hipStream_t stream) {
    const float* feats = (const float*)d_in[0];
    const float* mask  = (const float*)d_in[1];
    const int*   tags  = (const int*)d_in[2];
    const float* trans = (const float*)d_in[3];
    float* out = (float*)d_out;

    const int S = 512;              // reference shape
    const int B = in_sizes[1] / S;  // mask is (B,S)
    const int L = S / NSEG;         // 16 segments of 32 steps
    const int nchain = 30 * (B / 16);

    float* seg = (float*)d_ws;                       // [30][B][64]
    int* es = (int*)(seg + (size_t)30 * B * NTAGS);  // [30][B]
    float* gs = (float*)(es + 30 * B);               // [B]
    float* scores = gs + B;                          // [B]

    crf_chains<<<nchain + B, 64, 0, stream>>>(feats, mask, tags, trans,
                                              seg, es, gs, S, L, B, nchain);
    crf_finish<<<(B + 7) / 8, 512, 0, stream>>>(seg, es, gs, scores, B);
    crf_mean<<<1, 1024, 0, stream>>>(scores, out, B);
}